// Round 1
// baseline (189.820 us; speedup 1.0000x reference)
//
#include <hip/hip_runtime.h>

// MCLLoss: loss over 5 overlapping value-ranges of real_img.
// Ranges: (-1,1), (-1,-.5), (-.5,0), (0,.5), (.5,1) — inclusive bounds,
// masks overlap; class_mask takes the LAST matching range index.
// Output: [loss, losses[5], class_mask_rescaled[N]] ; rescale = cls*0.5-1.

__global__ __launch_bounds__(256) void mcl_main(
    const float* __restrict__ pre, const float* __restrict__ real,
    float* __restrict__ mask_out, float* __restrict__ sums,
    unsigned int* __restrict__ counts, int n4, int n)
{
    float s[5] = {0.f, 0.f, 0.f, 0.f, 0.f};
    unsigned int c[5] = {0u, 0u, 0u, 0u, 0u};

    const int tid = blockIdx.x * blockDim.x + threadIdx.x;
    const int stride = gridDim.x * blockDim.x;

    for (int i = tid; i < n4; i += stride) {
        float4 p = ((const float4*)pre)[i];
        float4 r = ((const float4*)real)[i];
        float pv[4] = {p.x, p.y, p.z, p.w};
        float rv[4] = {r.x, r.y, r.z, r.w};
        float ov[4];
#pragma unroll
        for (int k = 0; k < 4; ++k) {
            float rr = rv[k];
            float d = fabsf(pv[k] - rr);
            bool in0 = (rr >= -1.0f) && (rr <= 1.0f);
            bool in1 = (rr >= -1.0f) && (rr <= -0.5f);
            bool in2 = (rr >= -0.5f) && (rr <= 0.0f);
            bool in3 = (rr >= 0.0f) && (rr <= 0.5f);
            bool in4 = (rr >= 0.5f) && (rr <= 1.0f);
            s[0] += in0 ? d : 0.f; c[0] += in0;
            s[1] += in1 ? d : 0.f; c[1] += in1;
            s[2] += in2 ? d : 0.f; c[2] += in2;
            s[3] += in3 ? d : 0.f; c[3] += in3;
            s[4] += in4 ? d : 0.f; c[4] += in4;
            int cls = in4 ? 4 : (in3 ? 3 : (in2 ? 2 : (in1 ? 1 : 0)));
            ov[k] = 0.5f * (float)cls - 1.0f;
        }
        // mask_out = d_out+6 floats: only 8-byte aligned -> float2 stores.
        float2* mo = (float2*)(mask_out + 4 * (size_t)i);
        mo[0] = make_float2(ov[0], ov[1]);
        mo[1] = make_float2(ov[2], ov[3]);
    }

    // scalar tail (n not divisible by 4) — one element per leading thread
    int tail_base = n4 * 4;
    int tail = n - tail_base;
    if (tid < tail) {
        int idx = tail_base + tid;
        float rr = real[idx];
        float d = fabsf(pre[idx] - rr);
        bool in0 = (rr >= -1.0f) && (rr <= 1.0f);
        bool in1 = (rr >= -1.0f) && (rr <= -0.5f);
        bool in2 = (rr >= -0.5f) && (rr <= 0.0f);
        bool in3 = (rr >= 0.0f) && (rr <= 0.5f);
        bool in4 = (rr >= 0.5f) && (rr <= 1.0f);
        s[0] += in0 ? d : 0.f; c[0] += in0;
        s[1] += in1 ? d : 0.f; c[1] += in1;
        s[2] += in2 ? d : 0.f; c[2] += in2;
        s[3] += in3 ? d : 0.f; c[3] += in3;
        s[4] += in4 ? d : 0.f; c[4] += in4;
        int cls = in4 ? 4 : (in3 ? 3 : (in2 ? 2 : (in1 ? 1 : 0)));
        mask_out[idx] = 0.5f * (float)cls - 1.0f;
    }

    // wave64 butterfly reduction
#pragma unroll
    for (int j = 0; j < 5; ++j) {
#pragma unroll
        for (int off = 32; off > 0; off >>= 1) {
            s[j] += __shfl_down(s[j], off, 64);
            c[j] += __shfl_down(c[j], off, 64);
        }
    }

    __shared__ float ls[4][5];
    __shared__ unsigned int lc[4][5];
    int lane = threadIdx.x & 63;
    int wave = threadIdx.x >> 6;
    if (lane == 0) {
#pragma unroll
        for (int j = 0; j < 5; ++j) { ls[wave][j] = s[j]; lc[wave][j] = c[j]; }
    }
    __syncthreads();
    if (threadIdx.x < 5) {
        float ssum = ls[0][threadIdx.x] + ls[1][threadIdx.x]
                   + ls[2][threadIdx.x] + ls[3][threadIdx.x];
        unsigned int csum = lc[0][threadIdx.x] + lc[1][threadIdx.x]
                          + lc[2][threadIdx.x] + lc[3][threadIdx.x];
        atomicAdd(&sums[threadIdx.x], ssum);        // device-scope by default
        atomicAdd(&counts[threadIdx.x], csum);
    }
}

__global__ void mcl_final(const float* __restrict__ sums,
                          const unsigned int* __restrict__ counts,
                          float* __restrict__ out)
{
    if (threadIdx.x == 0) {
        float total = 0.f;
        float losses[5];
#pragma unroll
        for (int j = 0; j < 5; ++j) {
            unsigned int cnt = counts[j];
            unsigned int denom = cnt > 1u ? cnt : 1u;
            float l = (cnt == 0u) ? 0.f : (sums[j] / (float)denom) * 0.2f;
            losses[j] = l;
            total += l;
        }
        out[0] = total;
#pragma unroll
        for (int j = 0; j < 5; ++j) out[1 + j] = losses[j];
    }
}

extern "C" void kernel_launch(void* const* d_in, const int* in_sizes, int n_in,
                              void* d_out, int out_size, void* d_ws, size_t ws_size,
                              hipStream_t stream) {
    const float* pre  = (const float*)d_in[0];
    const float* real = (const float*)d_in[1];
    float* out = (float*)d_out;
    int n = in_sizes[0];
    int n4 = n / 4;

    float* sums = (float*)d_ws;
    unsigned int* counts = (unsigned int*)((char*)d_ws + 5 * sizeof(float));

    // d_ws is re-poisoned to 0xAA before every timed call — zero each launch.
    hipMemsetAsync(d_ws, 0, 10 * sizeof(float), stream);

    const int blocks = 1024;  // grid-stride; 10k total atomics, ~1k/address
    mcl_main<<<blocks, 256, 0, stream>>>(pre, real, out + 6, sums, counts, n4, n);
    mcl_final<<<1, 64, 0, stream>>>(sums, counts, out);
}